// Round 7
// baseline (269.683 us; speedup 1.0000x reference)
//
#include <hip/hip_runtime.h>

// StepConditionalLoReFT: out = h + Rn^T (W h + b - Rn h) per step s.
// All tensors FP32 (per reference). B=8 S=50 T=77 D=1024 r=16.
//
// Two kernels:
//  1) loreft_prep (50 blocks): Rn = R/max(||R||,eps), M = W - Rn -> bf16 in
//     workspace: Mg[s][r][d] (GEMM1 B-frag order), Rg[s][d][r] (GEMM2 A-frag
//     order). 3.3 MB total -> L2-resident for the main kernel.
//  2) loreft_main (grid 39 x 50, 256 thr = 4 waves, 32 KB LDS):
//     h 16-token tile staged ONCE as BF16 (reg-staged: 16 global_load_dwordx4
//     issued up-front per thread -> 64 KB/block in flight; ds_write makes the
//     loads un-sinkable, fixing rounds 2/5's VGPR=52 no-loads-in-flight wall).
//     32 KB LDS -> 4 blocks/CU = 16 waves/CU (2x round 6's occupancy).
//     Conversion f32->bf16 happens once per element in staging, so GEMM1's
//     inner loop is pure ds_read_b128 + MFMA (round 6 converted 4x per block
//     in the hot loop -> VALUBusy 15.6%). Epilogue h f32 re-read from global
//     (same-block L2/L3 hit; h is L3-resident per round-6 FETCH=75MB).

typedef __attribute__((ext_vector_type(8))) short short8;
typedef __attribute__((ext_vector_type(4))) float floatx4;

__device__ __forceinline__ short f2bf(float f) {
  unsigned u = __float_as_uint(f);
  u += 0x7fffu + ((u >> 16) & 1u);   // round-to-nearest-even
  return (short)(u >> 16);
}

#define S_ 50
#define T_ 77
#define NTOK 616   // B*T tokens per step s

// ================= prep kernel =================
__global__ __launch_bounds__(256) void loreft_prep(
    const float* __restrict__ RG, const float* __restrict__ WG,
    short* __restrict__ Mg, short* __restrict__ Rg) {
  __shared__ float RnL[16][1024];
  const int s = blockIdx.x;
  const int tid = threadIdx.x;
  const int lane = tid & 63;
  const int wvi = tid >> 6;

#pragma unroll
  for (int rr = 0; rr < 4; ++rr) {
    const int r = wvi * 4 + rr;
    const floatx4* Rrow = (const floatx4*)(RG + (size_t)((s * 16 + r) << 10));
    const floatx4* Wrow = (const floatx4*)(WG + (size_t)((s * 16 + r) << 10));
    floatx4 rv0 = Rrow[lane * 4 + 0];
    floatx4 rv1 = Rrow[lane * 4 + 1];
    floatx4 rv2 = Rrow[lane * 4 + 2];
    floatx4 rv3 = Rrow[lane * 4 + 3];
    float ss = 0.f;
#pragma unroll
    for (int j = 0; j < 4; ++j)
      ss += rv0[j] * rv0[j] + rv1[j] * rv1[j] + rv2[j] * rv2[j] + rv3[j] * rv3[j];
#pragma unroll
    for (int m = 1; m < 64; m <<= 1) ss += __shfl_xor(ss, m);
    const float inv = 1.0f / fmaxf(sqrtf(ss), 1e-12f);

    floatx4 wa0 = Wrow[lane * 4 + 0];
    floatx4 wa1 = Wrow[lane * 4 + 1];
    floatx4 wa2 = Wrow[lane * 4 + 2];
    floatx4 wa3 = Wrow[lane * 4 + 3];
    float rn[16];
    short8 m0, m1;
#pragma unroll
    for (int j = 0; j < 4; ++j) {
      rn[j]      = rv0[j] * inv;  m0[j]     = f2bf(wa0[j] - rn[j]);
      rn[4 + j]  = rv1[j] * inv;  m0[4 + j] = f2bf(wa1[j] - rn[4 + j]);
      rn[8 + j]  = rv2[j] * inv;  m1[j]     = f2bf(wa2[j] - rn[8 + j]);
      rn[12 + j] = rv3[j] * inv;  m1[4 + j] = f2bf(wa3[j] - rn[12 + j]);
    }
    // Mg[s][r][d] row-major bf16, lane covers d = lane*16 .. +15
    short* mdst = Mg + (size_t)(s * 16 + r) * 1024 + lane * 16;
    *(short8*)mdst = m0;
    *(short8*)(mdst + 8) = m1;
#pragma unroll
    for (int jj = 0; jj < 16; ++jj) RnL[r][lane * 16 + jj] = rn[jj];
  }
  __syncthreads();

  // Rg[s][d][r]: thread handles d = dd*256 + tid, writes 16 r-values (32 B)
#pragma unroll
  for (int dd = 0; dd < 4; ++dd) {
    const int d = dd * 256 + tid;
    short8 lo8, hi8;
#pragma unroll
    for (int rj = 0; rj < 8; ++rj) {
      lo8[rj] = f2bf(RnL[rj][d]);
      hi8[rj] = f2bf(RnL[rj + 8][d]);
    }
    short* dst = Rg + ((size_t)s * 1024 + d) * 16;
    *(short8*)dst = lo8;
    *(short8*)(dst + 8) = hi8;
  }
}

// ===== main kernel: bf16 LDS-staged h tile, 4 waves, one barrier ==========
__global__ __launch_bounds__(256, 4) void loreft_main(
    const float* __restrict__ hG, const float* __restrict__ bG,
    const short* __restrict__ Mg, const short* __restrict__ Rg,
    float* __restrict__ outG) {
  // h tile as bf16: 16 rows x 1024 = 32 KB. 16B-block b of row r stored at
  // physical block (b ^ (r&7)).
  __shared__ short hB[16 * 1024];

  const int tid = threadIdx.x;
  const int lane = tid & 63;
  const int wvi = tid >> 6;       // wave 0..3
  const int m16 = lane & 15;
  const int quad = lane >> 4;
  const int tile = blockIdx.x;    // 39 tiles cover 616 tokens
  const int s = blockIdx.y;
  const int tokbase = tile * 16;

  // ---------- stage: issue ALL 16 global_load_dwordx4 up front ----------
  // thread tid covers elements e = it*2048 + tid*8 (rows 2*it + tid/128).
  floatx4 st[16];
#pragma unroll
  for (int it = 0; it < 8; ++it) {
    const int e = it * 2048 + tid * 8;
    const int row = e >> 10;
    const int col = e & 1023;
    int tok = tokbase + row; if (tok > NTOK - 1) tok = NTOK - 1;
    const int bb = tok / T_;
    const int tt = tok - bb * T_;
    const float* src = hG + (((size_t)((bb * S_ + s) * T_ + tt)) << 10) + col;
    st[2 * it]     = *(const floatx4*)(src);
    st[2 * it + 1] = *(const floatx4*)(src + 4);
  }
  // convert + swizzled ds_write (consumes loads in order; 64KB/block in flight)
#pragma unroll
  for (int it = 0; it < 8; ++it) {
    short8 v;
#pragma unroll
    for (int i = 0; i < 4; ++i) {
      v[i]     = f2bf(st[2 * it][i]);
      v[4 + i] = f2bf(st[2 * it + 1][i]);
    }
    const int e = it * 2048 + tid * 8;
    const int row = e >> 10;
    const int b = (e & 1023) >> 3;
    *(short8*)(hB + row * 1024 + ((b ^ (row & 7)) << 3)) = v;
  }

  // per-lane row offset for stores/epilogue, while staging completes
  int tokA = tokbase + m16; if (tokA > NTOK - 1) tokA = NTOK - 1;
  const int bb1 = tokA / T_;
  const int tt1 = tokA - bb1 * T_;
  const size_t rowoff = ((size_t)((bb1 * S_ + s) * T_ + tt1)) << 10;
  const float* hrow = hG + rowoff;
  // GEMM1 B-frag: lane (quad,m16) needs M[r=m16][k = kb*32 + quad*8 + j]
  const short* mrow = Mg + (size_t)(s * 16 + m16) * 1024 + quad * 8;
  const float bias = bG[s * 16 + m16];
  const int sw = m16 & 7;
  const short* hls = hB + m16 * 1024;   // this lane's h row in LDS (bf16)

  __syncthreads();   // staging complete

  // ---------- GEMM1: c[tok, r] = H M^T (A-frags straight from LDS) ------
  floatx4 acc = {0.f, 0.f, 0.f, 0.f};
#pragma unroll
  for (int kg = 0; kg < 4; ++kg) {
    short8 mf[8];
#pragma unroll
    for (int j = 0; j < 8; ++j)          // 8 independent L2 loads
      mf[j] = *(const short8*)(mrow + (kg * 8 + j) * 32);
#pragma unroll
    for (int j = 0; j < 8; ++j) {
      const int kb = kg * 8 + j;
      short8 af = *(const short8*)(hls + (((kb * 4 + quad) ^ sw) << 3));
      acc = __builtin_amdgcn_mfma_f32_16x16x32_bf16(af, mf[j], acc, 0, 0, 0);
    }
  }

  // c: lane holds c[tok = quad*4 + i][r = m16]; add bias b[s][r]
  float cf[4];
#pragma unroll
  for (int i = 0; i < 4; ++i) cf[i] = acc[i] + bias;

  // ========== transpose c -> B-frag of GEMM2-T via shuffles ==========
  // target lane L needs B[k=r=(L>>4)*8+j][n=tok=L&15] = c[tok][r];
  // source lane = (tok>>2)*16 + r, reg = tok&3.
  unsigned lo = ((unsigned)(unsigned short)f2bf(cf[0])) |
                (((unsigned)(unsigned short)f2bf(cf[1])) << 16);
  unsigned hi = ((unsigned)(unsigned short)f2bf(cf[2])) |
                (((unsigned)(unsigned short)f2bf(cf[3])) << 16);
  short8 bfrag;
  {
    const int srcbase = ((m16 >> 2) << 4) + ((quad & 1) << 3);
    const int regsel = m16 & 3;
#pragma unroll
    for (int j = 0; j < 8; ++j) {
      unsigned vlo = __shfl(lo, srcbase + j);
      unsigned vhi = __shfl(hi, srcbase + j);
      unsigned v32 = (regsel & 2) ? vhi : vlo;
      bfrag[j] = (short)((regsel & 1) ? (v32 >> 16) : (v32 & 0xffffu));
    }
  }
  const short8 zero8 = {0, 0, 0, 0, 0, 0, 0, 0};
  if (quad >= 2) bfrag = zero8;   // k = r in [16,32) is padding

  // ========== GEMM2-T + epilogue: this wave owns dt = wvi*16 .. +15 ======
  // A-frag: lane needs Rn^T[d = dt*16 + m16][r = q16 .. q16+7] (quads 2/3 zero)
  // D: lane holds delta[d = dt*16 + quad*4 + i][tok = m16]; h f32 from
  // global (L2/L3 hit -- staged microseconds ago, h is L3-resident).
  float* orow = outG + rowoff;
  const bool valE = (tokbase + m16) < NTOK;
  const int q16 = (quad & 1) << 3;
  const short* rbase = Rg + (size_t)s * (1024 * 16) + q16;
  const int dt0 = wvi * 16;

  short8 ar[4];
  floatx4 hv[4];
#pragma unroll
  for (int j = 0; j < 4; ++j) {                 // prologue: group 0
    const int dt = dt0 + j;
    ar[j] = (quad < 2) ? *(const short8*)(rbase + (dt * 16 + m16) * 16) : zero8;
    hv[j] = *(const floatx4*)(hrow + dt * 16 + quad * 4);
  }
#pragma unroll
  for (int g = 0; g < 4; ++g) {
    short8 nr[4];
    floatx4 nh[4];
    if (g < 3) {
#pragma unroll
      for (int j = 0; j < 4; ++j) {             // issue next group's loads
        const int dt = dt0 + (g + 1) * 4 + j;
        nr[j] = (quad < 2) ? *(const short8*)(rbase + (dt * 16 + m16) * 16) : zero8;
        nh[j] = *(const floatx4*)(hrow + dt * 16 + quad * 4);
      }
    }
#pragma unroll
    for (int j = 0; j < 4; ++j) {               // compute + store current
      const int dt = dt0 + g * 4 + j;
      floatx4 z = {0.f, 0.f, 0.f, 0.f};
      floatx4 dv = __builtin_amdgcn_mfma_f32_16x16x32_bf16(ar[j], bfrag, z, 0, 0, 0);
      if (valE) {
        floatx4 o;
#pragma unroll
        for (int i = 0; i < 4; ++i) o[i] = hv[j][i] + dv[i];
        *(floatx4*)(orow + dt * 16 + quad * 4) = o;
      }
    }
    if (g < 3) {
#pragma unroll
      for (int j = 0; j < 4; ++j) { ar[j] = nr[j]; hv[j] = nh[j]; }
    }
  }
}

extern "C" void kernel_launch(void* const* d_in, const int* in_sizes, int n_in,
                              void* d_out, int out_size, void* d_ws, size_t ws_size,
                              hipStream_t stream) {
  const float* h = (const float*)d_in[0];
  const float* R = (const float*)d_in[1];
  const float* W = (const float*)d_in[2];
  const float* b = (const float*)d_in[3];
  // workspace: Mg (50*16*1024 bf16 = 1.64 MB) then Rg (same) = 3.28 MB total
  short* Mg = (short*)d_ws;
  short* Rg = Mg + (size_t)S_ * 16 * 1024;
  loreft_prep<<<dim3(S_), 256, 0, stream>>>(R, W, Mg, Rg);
  loreft_main<<<dim3(39, S_), 256, 0, stream>>>(h, b, Mg, Rg, (float*)d_out);
}

// Round 8
// 261.940 us; speedup vs baseline: 1.0296x; 1.0296x over previous
//
#include <hip/hip_runtime.h>

// StepConditionalLoReFT: out = h + Rn^T (W h + b - Rn h) per step s.
// All tensors FP32 (per reference). B=8 S=50 T=77 D=1024 r=16.
//
// Round-8 structure (fixes the in-order-vmcnt prefetch drain that capped all
// prior rounds at ~2.4 TB/s):
//  1) loreft_prep (50 blocks): Rn, M = W - Rn -> bf16 workspace Mg[s][r][d],
//     Rg[s][d][r]. Unchanged.
//  2) loreft_main: PERSISTENT blocks, grid (5, 50) = 250 blocks (~1/CU),
//     each owns one s and tiles tl = bx, bx+5, ... (8-token tiles; 616 = 77*8
//     exactly -> no tail). 160 KB LDS:
//       Mg[s] 32K + Rg[s] 32K (staged once per block)
//       h f32 tile: 3 x 32K triple buffer, staged 2-AHEAD via global_load_lds.
//     The compute phase is PURE LDS + MFMA (no VMEM reads): GEMM1 A from LDS
//     f32 (cvt in loop) + M from LDS; GEMM2 Rn^T from LDS; epilogue h from
//     LDS with out = mfma(ar, bfrag, C=h_frag) fusing the residual add.
//     Hence no VMEM-read consume ever drains the staged HBM loads (vmcnt is
//     in-order), and each tile's 32 KB stage flies for a full compute phase.
//     One __syncthreads per tile. All LDS tiles XOR-swizzled via pre-swizzled
//     GLOBAL source addresses (linear LDS dest), conflict-free reads.

typedef __attribute__((ext_vector_type(8))) short short8;
typedef __attribute__((ext_vector_type(4))) float floatx4;

__device__ __forceinline__ short f2bf(float f) {
  unsigned u = __float_as_uint(f);
  u += 0x7fffu + ((u >> 16) & 1u);   // round-to-nearest-even
  return (short)(u >> 16);
}

#define S_ 50
#define T_ 77
#define NTOK 616   // B*T tokens per step s; 77 tiles of 8 tokens exactly

// ================= prep kernel (unchanged) =================
__global__ __launch_bounds__(256) void loreft_prep(
    const float* __restrict__ RG, const float* __restrict__ WG,
    short* __restrict__ Mg, short* __restrict__ Rg) {
  __shared__ float RnL[16][1024];
  const int s = blockIdx.x;
  const int tid = threadIdx.x;
  const int lane = tid & 63;
  const int wvi = tid >> 6;

#pragma unroll
  for (int rr = 0; rr < 4; ++rr) {
    const int r = wvi * 4 + rr;
    const floatx4* Rrow = (const floatx4*)(RG + (size_t)((s * 16 + r) << 10));
    const floatx4* Wrow = (const floatx4*)(WG + (size_t)((s * 16 + r) << 10));
    floatx4 rv0 = Rrow[lane * 4 + 0];
    floatx4 rv1 = Rrow[lane * 4 + 1];
    floatx4 rv2 = Rrow[lane * 4 + 2];
    floatx4 rv3 = Rrow[lane * 4 + 3];
    float ss = 0.f;
#pragma unroll
    for (int j = 0; j < 4; ++j)
      ss += rv0[j] * rv0[j] + rv1[j] * rv1[j] + rv2[j] * rv2[j] + rv3[j] * rv3[j];
#pragma unroll
    for (int m = 1; m < 64; m <<= 1) ss += __shfl_xor(ss, m);
    const float inv = 1.0f / fmaxf(sqrtf(ss), 1e-12f);

    floatx4 wa0 = Wrow[lane * 4 + 0];
    floatx4 wa1 = Wrow[lane * 4 + 1];
    floatx4 wa2 = Wrow[lane * 4 + 2];
    floatx4 wa3 = Wrow[lane * 4 + 3];
    float rn[16];
    short8 m0, m1;
#pragma unroll
    for (int j = 0; j < 4; ++j) {
      rn[j]      = rv0[j] * inv;  m0[j]     = f2bf(wa0[j] - rn[j]);
      rn[4 + j]  = rv1[j] * inv;  m0[4 + j] = f2bf(wa1[j] - rn[4 + j]);
      rn[8 + j]  = rv2[j] * inv;  m1[j]     = f2bf(wa2[j] - rn[8 + j]);
      rn[12 + j] = rv3[j] * inv;  m1[4 + j] = f2bf(wa3[j] - rn[12 + j]);
    }
    short* mdst = Mg + (size_t)(s * 16 + r) * 1024 + lane * 16;
    *(short8*)mdst = m0;
    *(short8*)(mdst + 8) = m1;
#pragma unroll
    for (int jj = 0; jj < 16; ++jj) RnL[r][lane * 16 + jj] = rn[jj];
  }
  __syncthreads();

#pragma unroll
  for (int dd = 0; dd < 4; ++dd) {
    const int d = dd * 256 + tid;
    short8 lo8, hi8;
#pragma unroll
    for (int rj = 0; rj < 8; ++rj) {
      lo8[rj] = f2bf(RnL[rj][d]);
      hi8[rj] = f2bf(RnL[rj + 8][d]);
    }
    short* dst = Rg + ((size_t)s * 1024 + d) * 16;
    *(short8*)dst = lo8;
    *(short8*)(dst + 8) = hi8;
  }
}

// ===== main kernel: persistent, all-LDS compute, triple-buffered stage =====
__global__ __launch_bounds__(256, 1) void loreft_main(
    const float* __restrict__ hG, const float* __restrict__ bG,
    const short* __restrict__ Mg, const short* __restrict__ Rg,
    float* __restrict__ outG) {
  extern __shared__ char smem[];
  short* sm_M = (short*)smem;            // 32 KB: M[r][d] bf16, blk^(r&7)
  const char* sm_Rb = smem + 32768;      // 32 KB: Rn^T[d][r] bf16, linear
  char* sm_h0 = smem + 65536;            // 3 x 32 KB: h f32 [8][1024], blk^row

  const int tid = threadIdx.x;
  const int lane = tid & 63;
  const int wvi = tid >> 6;       // wave 0..3
  const int m16 = lane & 15;
  const int quad = lane >> 4;
  const int bx = blockIdx.x;      // 0..4: tile stride group
  const int s = blockIdx.y;
  const int nt = (77 - bx + 4) / 5;   // 16,16,15,15,15

  // ---- stage Mg (pre-swizzled source -> linear LDS dest) ----
#pragma unroll
  for (int it = 0; it < 8; ++it) {
    const int L = it * 4096 + tid * 16;          // byte offset in sm_M
    const int r = L >> 11;                        // 2048 B per row
    const int pb = (L & 2047) >> 4;               // phys 16B block
    const int sb = pb ^ (r & 7);                  // logical block at phys
    const short* src = Mg + (size_t)(s * 16 + r) * 1024 + sb * 8;
    __builtin_amdgcn_global_load_lds(
        (const __attribute__((address_space(1))) void*)src,
        (__attribute__((address_space(3))) void*)((char*)sm_M + L), 16, 0, 0);
  }
  // ---- stage Rg (linear copy) ----
#pragma unroll
  for (int it = 0; it < 8; ++it) {
    const int L = it * 4096 + tid * 16;
    const short* src = Rg + (size_t)s * 16384 + (L >> 1);
    __builtin_amdgcn_global_load_lds(
        (const __attribute__((address_space(1))) void*)src,
        (__attribute__((address_space(3))) void*)((char*)sm_Rb + L), 16, 0, 0);
  }

  // ---- h tile stage: 8 rows x 4096 B, 16B block b of row r at phys b^r ----
  auto stage_h = [&](int tl, char* hbuf) {
#pragma unroll
    for (int it = 0; it < 8; ++it) {              // row = it
      const int tok = tl * 8 + it;                // always < 616
      const int bb = tok / T_;
      const int tt = tok - bb * T_;
      const float* src = hG + (((size_t)((bb * S_ + s) * T_ + tt)) << 10)
                           + ((tid ^ it) << 2);   // pre-swizzled logical block
      __builtin_amdgcn_global_load_lds(
          (const __attribute__((address_space(1))) void*)src,
          (__attribute__((address_space(3))) void*)(hbuf + it * 4096 + tid * 16),
          16, 0, 0);
    }
  };

  stage_h(bx, sm_h0);                              // tile 0 -> buf 0
  if (nt > 1) stage_h(bx + 5, sm_h0 + 32768);      // tile 1 -> buf 1
  __syncthreads();                                 // drains all staging

  const int sw = m16 & 7;          // swizzle key / A-row (tokens 0..7)
  const float bias = bG[s * 16 + m16];
  const short8 zero8 = {0, 0, 0, 0, 0, 0, 0, 0};
  const int dt0 = wvi * 16;        // this wave's GEMM2 d-range

  for (int i = 0; i < nt; ++i) {
    const int tl = bx + 5 * i;
    if (i + 2 < nt)                                // 2-ahead prefetch
      stage_h(bx + 5 * (i + 2), sm_h0 + ((i + 2) % 3) * 32768);

    const char* ha = sm_h0 + (i % 3) * 32768 + sw * 4096;  // lane's h row

    // ---------- GEMM1: c[tok, r] = H M^T (pure LDS) ----------
    floatx4 acc = {0.f, 0.f, 0.f, 0.f};
#pragma unroll
    for (int kb = 0; kb < 32; ++kb) {
      const int b0 = kb * 8 + quad * 2;
      floatx4 p0 = *(const floatx4*)(ha + ((b0 ^ sw) << 4));
      floatx4 p1 = *(const floatx4*)(ha + (((b0 + 1) ^ sw) << 4));
      short8 bf = *(const short8*)((const char*)sm_M + m16 * 2048 +
                                   (((kb * 4 + quad) ^ sw) << 4));
      short8 af;
#pragma unroll
      for (int j = 0; j < 4; ++j) { af[j] = f2bf(p0[j]); af[4 + j] = f2bf(p1[j]); }
      acc = __builtin_amdgcn_mfma_f32_16x16x32_bf16(af, bf, acc, 0, 0, 0);
    }
    float cf[4];
#pragma unroll
    for (int j = 0; j < 4; ++j) cf[j] = acc[j] + bias;

    // ---------- transpose c -> B-frag of GEMM2-T via shuffles ----------
    unsigned lo = ((unsigned)(unsigned short)f2bf(cf[0])) |
                  (((unsigned)(unsigned short)f2bf(cf[1])) << 16);
    unsigned hi = ((unsigned)(unsigned short)f2bf(cf[2])) |
                  (((unsigned)(unsigned short)f2bf(cf[3])) << 16);
    short8 bfrag;
    {
      const int srcbase = ((m16 >> 2) << 4) + ((quad & 1) << 3);
      const int regsel = m16 & 3;
#pragma unroll
      for (int j = 0; j < 8; ++j) {
        unsigned vlo = __shfl(lo, srcbase + j);
        unsigned vhi = __shfl(hi, srcbase + j);
        unsigned v32 = (regsel & 2) ? vhi : vlo;
        bfrag[j] = (short)((regsel & 1) ? (v32 >> 16) : (v32 & 0xffffu));
      }
    }
    if (quad >= 2) bfrag = zero8;   // k = r in [16,32) is padding

    // ---------- GEMM2-T + fused epilogue (pure LDS + stores) ----------
    // C-in = h fragment from LDS -> D = h + delta directly.
    const int tokS = tl * 8 + sw;
    const int bbS = tokS / T_;
    const int ttS = tokS - bbS * T_;
    float* orow = outG + (((size_t)((bbS * S_ + s) * T_ + ttS)) << 10);
    const bool doSt = (m16 < 8);
#pragma unroll
    for (int k = 0; k < 16; ++k) {
      const int dt = dt0 + k;
      short8 ar = zero8;
      if (quad < 2)
        ar = *(const short8*)(sm_Rb + (dt * 16 + m16) * 32 + ((quad & 1) << 4));
      floatx4 hv = *(const floatx4*)(ha + (((dt * 4 + quad) ^ sw) << 4));
      floatx4 dv = __builtin_amdgcn_mfma_f32_16x16x32_bf16(ar, bfrag, hv, 0, 0, 0);
      if (doSt) *(floatx4*)(orow + dt * 16 + quad * 4) = dv;
    }
    __syncthreads();   // all waves done with buf (i%3); stage (i+2) landed
  }
}

extern "C" void kernel_launch(void* const* d_in, const int* in_sizes, int n_in,
                              void* d_out, int out_size, void* d_ws, size_t ws_size,
                              hipStream_t stream) {
  const float* h = (const float*)d_in[0];
  const float* R = (const float*)d_in[1];
  const float* W = (const float*)d_in[2];
  const float* b = (const float*)d_in[3];
  short* Mg = (short*)d_ws;
  short* Rg = Mg + (size_t)S_ * 16 * 1024;

  static bool attr_set = false;
  if (!attr_set) {
    hipFuncSetAttribute((const void*)loreft_main,
                        hipFuncAttributeMaxDynamicSharedMemorySize, 163840);
    attr_set = true;
  }
  loreft_prep<<<dim3(S_), 256, 0, stream>>>(R, W, Mg, Rg);
  loreft_main<<<dim3(5, S_), 256, 163840, stream>>>(h, b, Mg, Rg, (float*)d_out);
}